// Round 8
// baseline (275.137 us; speedup 1.0000x reference)
//
#include <hip/hip_runtime.h>
#include <hip/hip_bf16.h>

#define NN 1024
#define DD 64
#define EE 16384
#define PP 8192
#define EPSF 1e-5f
#define SWP (DD + 8)   // padded LDS row stride in shorts (144 B)

typedef __hip_bfloat16 bf16;
typedef __attribute__((ext_vector_type(8))) short short8;
typedef __attribute__((ext_vector_type(4))) float f32x4;

static __device__ __forceinline__ float dec1(const void* src, int i, int fl) {
    if (fl) return ((const float*)src)[i];
    return __bfloat162float(((const bf16*)src)[i]);
}
static __device__ __forceinline__ unsigned short f2bf_u(float f) {
    bf16 h = __float2bfloat16(f);
    return *reinterpret_cast<unsigned short*>(&h);
}
static __device__ __forceinline__ float bfu2f(unsigned short u) {
    return __uint_as_float(((unsigned int)u) << 16);
}
static __device__ __forceinline__ int probe_fl(const void* emb) {
    int lane = threadIdx.x & 63;
    unsigned short raw = ((const unsigned short*)emb)[lane];
    float v = __uint_as_float(((unsigned int)raw) << 16);
    return (__ballot(!(fabsf(v) <= 1e3f)) != 0ull) ? 1 : 0;
}

// =============== K1: decode everything + embed + zero bitmaps + CSR build ===============
// blocks 0..387: decode/embed roles (blocks <256 also zero eim/eimT)
// block 388: single-block CSR build (deg in LDS, scan, scatter)
__global__ __launch_bounds__(256) void k_prep(
        const void* __restrict__ emb, const void* __restrict__ sWl,
        const void* __restrict__ sbl, const void* __restrict__ sWr,
        const void* __restrict__ hW, const void* __restrict__ hb,
        const void* __restrict__ gW, const void* __restrict__ gb,
        const void* __restrict__ lW, const void* __restrict__ lb,
        const int* __restrict__ x, const int* __restrict__ ei,
        float* __restrict__ Wlf, float* __restrict__ blf, float* __restrict__ Wrf,
        float* __restrict__ WfT, float* __restrict__ hbw,
        float* __restrict__ gWf, float* __restrict__ linf,
        float* __restrict__ h0,
        unsigned int* __restrict__ eim, unsigned int* __restrict__ eimT,
        int* __restrict__ rowptr, int* __restrict__ csrc) {
    __shared__ int sdeg[NN];
    __shared__ int stmp[256];
    const int b = blockIdx.x, tid = threadIdx.x;
    const int fl = probe_fl(emb);

    // zero the edge bitmaps (65536 words over blocks 0..255)
    if (b < 256) {
        int z = b * 256 + tid;
        if (z < 32768) eim[z] = 0u;
        else           eimT[z - 32768] = 0u;
    }

    if (b < 32) { int i = b * 256 + tid; Wlf[i] = dec1(sWl, i, fl); }
    else if (b == 32) { if (tid < 128) blf[tid] = dec1(sbl, tid, fl); }
    else if (b < 65) { int i = (b - 33) * 256 + tid; Wrf[i] = dec1(sWr, i, fl); }
    else if (b < 82) {
        int i = (b - 65) * 256 + tid;
        if (i < 4096) { int n = i >> 6, k = i & 63; WfT[n * DD + k] = dec1(hW, k * DD + n, fl); }
        else if (i < 4160) hbw[i - 4096] = dec1(hb, i - 4096, fl);
        else if (i < 4224) hbw[64 + (i - 4160)] = dec1(hW, 64 * DD + (i - 4160), fl);
    } else if (b < 131) {
        int i = (b - 82) * 256 + tid;
        if (i < 193 * DD) gWf[i] = dec1(gW, i, fl);
        else if (i < 194 * DD) gWf[i] = dec1(gb, i - 193 * DD, fl);
    } else if (b == 131) {
        if (tid < DD) linf[tid] = dec1(lW, tid, fl);
        else if (tid == DD) linf[DD] = dec1(lb, 0, fl);
    } else if (b < 388) {
        int i = (b - 132) * 256 + tid;
        int node = i >> 6, f = i & 63;
        h0[i] = dec1(emb, x[node] * DD + f, fl);
    } else if (b == 388) {
        // ---- CSR build, single block ----
        for (int i = tid; i < NN; i += 256) sdeg[i] = 0;
        __syncthreads();
        for (int e = tid; e < EE; e += 256) atomicAdd(&sdeg[ei[EE + e]], 1);
        __syncthreads();
        int base4 = tid * 4;
        int v[4]; int s = 0;
#pragma unroll
        for (int u = 0; u < 4; ++u) { v[u] = sdeg[base4 + u]; s += v[u]; }
        stmp[tid] = s;
        __syncthreads();
        for (int off = 1; off < 256; off <<= 1) {
            int a = (tid >= off) ? stmp[tid - off] : 0;
            __syncthreads();
            stmp[tid] += a;
            __syncthreads();
        }
        int run = stmp[tid] - s;
#pragma unroll
        for (int u = 0; u < 4; ++u) {
            rowptr[base4 + u] = run;
            sdeg[base4 + u] = run;    // becomes cursor
            run += v[u];
        }
        if (tid == 255) rowptr[NN] = run;
        __syncthreads();
        for (int e = tid; e < EE; e += 256) {
            int d = ei[EE + e];
            int c = atomicAdd(&sdeg[d], 1);
            csrc[c] = ei[e];
        }
    }
}

// =============== shared SAGE body (one wave per node) ===============
static __device__ __forceinline__ void sage_body(
        char* smem, int node, int lane, int wave,
        const int* __restrict__ rowptr, const int* __restrict__ csrc,
        const float* __restrict__ hin,
        const float* __restrict__ Wl, const float* __restrict__ bl,
        const float* __restrict__ Wr,
        float* __restrict__ hout, unsigned short* __restrict__ hbf) {
    float* sa = (float*)smem + wave * 2 * DD;
    float* sh = sa + DD;
    int r0 = rowptr[node], r1 = rowptr[node + 1];
    float s = 0.f;
    for (int r = r0; r < r1; ++r) s += hin[csrc[r] * DD + lane];
    sa[lane] = s / (float)max(r1 - r0, 1);
    sh[lane] = hin[node * DD + lane];
    float o = bl[lane];
    for (int k = 0; k < DD; ++k)
        o += sa[k] * Wl[k * DD + lane] + sh[k] * Wr[k * DD + lane];
    float m = o;
    for (int off = 32; off; off >>= 1) m += __shfl_xor(m, off);
    m *= (1.f / DD);
    float d0 = o - m;
    float v = d0 * d0;
    for (int off = 32; off; off >>= 1) v += __shfl_xor(v, off);
    v *= (1.f / DD);
    float r = d0 * rsqrtf(v + EPSF);
    hout[node * DD + lane] = r;
    if (hbf) hbf[node * DD + lane] = f2bf_u(r);
}

// =============== K2: SAGE round 0 + edge-bitmap atomics ===============
__global__ __launch_bounds__(256) void k_sage0(
        const int* __restrict__ ei,
        const int* __restrict__ rowptr, const int* __restrict__ csrc,
        const float* __restrict__ h0,
        const float* __restrict__ Wlf, const float* __restrict__ blf,
        const float* __restrict__ Wrf,
        float* __restrict__ h1,
        unsigned int* __restrict__ eim, unsigned int* __restrict__ eimT) {
    __shared__ __align__(16) char smem[4 * 2 * DD * 4];
    const int b = blockIdx.x, tid = threadIdx.x;
    const int lane = tid & 63, wave = tid >> 6;
    if (tid < 64) {
        int e = b * 64 + tid;
        int s = ei[e], d = ei[EE + e];
        unsigned int idx = (unsigned int)(s * NN + d);
        atomicOr(&eim[idx >> 5], 1u << (idx & 31));
        unsigned int idxT = (unsigned int)(d * NN + s);
        atomicOr(&eimT[idxT >> 5], 1u << (idxT & 31));
    }
    sage_body(smem, b * 4 + wave, lane, wave, rowptr, csrc, h0, Wlf, blf, Wrf,
              h1, (unsigned short*)nullptr);
}

// =============== K3: SAGE round 1 (writes h2 + bf16 copy) ===============
__global__ __launch_bounds__(256) void k_sage1(
        const int* __restrict__ rowptr, const int* __restrict__ csrc,
        const float* __restrict__ h1,
        const float* __restrict__ Wlf, const float* __restrict__ blf,
        const float* __restrict__ Wrf,
        float* __restrict__ h2, unsigned short* __restrict__ hbf) {
    __shared__ __align__(16) char smem[4 * 2 * DD * 4];
    const int b = blockIdx.x, tid = threadIdx.x;
    const int lane = tid & 63, wave = tid >> 6;
    sage_body(smem, b * 4 + wave, lane, wave, rowptr, csrc, h1,
              Wlf + DD * DD, blf + DD, Wrf + DD * DD, h2, hbf);
}

// =============== K4: B-stage (MFMA) + fused pp/qq projection ===============
__global__ __launch_bounds__(256, 4) void k_bstage(
        const float* __restrict__ h2, const unsigned short* __restrict__ hbf,
        const float* __restrict__ WfT, const float* __restrict__ hbw,
        const unsigned int* __restrict__ eim, const unsigned int* __restrict__ eimT,
        const float* __restrict__ gWf,
        float* __restrict__ ppb, float* __restrict__ qqb) {
    __shared__ __align__(16) unsigned short sW[DD * SWP];  // 9216 B
    __shared__ __align__(16) float red[4 * 128];           // 2048 B
    const int b = blockIdx.x, tid = threadIdx.x;
    const int lane = tid & 63, wave = tid >> 6;
    const int l15 = lane & 15, quad = lane >> 4;

    {
        int m = tid >> 2;
        int k0 = (tid & 3) * 16;
        const float* hi = h2 + b * DD;
        const float* wr = WfT + m * DD;
        unsigned short tmp[16];
#pragma unroll
        for (int u = 0; u < 16; ++u) tmp[u] = f2bf_u(hi[k0 + u] * wr[k0 + u]);
        *(short8*)(sW + m * SWP + k0) = *(short8*)tmp;
        *(short8*)(sW + m * SWP + k0 + 8) = *(short8*)(tmp + 8);
    }
    __syncthreads();

    short8 Af[4][2];
#pragma unroll
    for (int mt = 0; mt < 4; ++mt)
#pragma unroll
        for (int kt = 0; kt < 2; ++kt)
            Af[mt][kt] = *(const short8*)(sW + (mt * 16 + l15) * SWP + kt * 32 + quad * 8);

    float hb0[4][4], hww[4][4];
#pragma unroll
    for (int mt = 0; mt < 4; ++mt) {
        f32x4 a = *(const f32x4*)(hbw + mt * 16 + quad * 4);
        f32x4 wv = *(const f32x4*)(hbw + 64 + mt * 16 + quad * 4);
#pragma unroll
        for (int r = 0; r < 4; ++r) { hb0[mt][r] = a[r]; hww[mt][r] = wv[r]; }
    }

    float accf[4][4], accb[4][4];
#pragma unroll
    for (int mt = 0; mt < 4; ++mt)
#pragma unroll
        for (int r = 0; r < 4; ++r) { accf[mt][r] = 0.f; accb[mt][r] = 0.f; }

    int g = wave;
    short8 B0 = *(const short8*)(hbf + (g * 16 + l15) * DD + quad * 8);
    short8 B1 = *(const short8*)(hbf + (g * 16 + l15) * DD + 32 + quad * 8);

    for (int it = 0; it < 16; ++it, g += 4) {
        short8 cB0 = B0, cB1 = B1;
        if (it < 15) {
            int gn = g + 4;
            B0 = *(const short8*)(hbf + (gn * 16 + l15) * DD + quad * 8);
            B1 = *(const short8*)(hbf + (gn * 16 + l15) * DD + 32 + quad * 8);
        }
        unsigned int base = (unsigned int)(b * NN + g * 16);
        unsigned int sf = (eim[base >> 5] >> (base & 31)) & 0xFFFFu;
        unsigned int sb = (eimT[base >> 5] >> (base & 31)) & 0xFFFFu;

        f32x4 C[4];
#pragma unroll
        for (int mt = 0; mt < 4; ++mt)
            C[mt] = (f32x4){hb0[mt][0], hb0[mt][1], hb0[mt][2], hb0[mt][3]};
#pragma unroll
        for (int mt = 0; mt < 4; ++mt)
            C[mt] = __builtin_amdgcn_mfma_f32_16x16x32_bf16(Af[mt][0], cB0, C[mt], 0, 0, 0);
#pragma unroll
        for (int mt = 0; mt < 4; ++mt)
            C[mt] = __builtin_amdgcn_mfma_f32_16x16x32_bf16(Af[mt][1], cB1, C[mt], 0, 0, 0);

        float ef = (float)((sf >> l15) & 1u);
        float s1 = 0.f, s2 = 0.f;
#pragma unroll
        for (int mt = 0; mt < 4; ++mt)
#pragma unroll
            for (int r = 0; r < 4; ++r) {
                float v = C[mt][r] + ef * hww[mt][r];
                C[mt][r] = v;
                s1 += v;
                s2 += v * v;
            }
        s1 += __shfl_xor(s1, 16); s1 += __shfl_xor(s1, 32);
        s2 += __shfl_xor(s2, 16); s2 += __shfl_xor(s2, 32);
        float mean = s1 * (1.f / DD);
        float var = fmaxf(s2 * (1.f / DD) - mean * mean, 0.f);
        float rs = rsqrtf(var + EPSF);
        float mrs = mean * rs;

        if (sf == sb) {
#pragma unroll
            for (int mt = 0; mt < 4; ++mt)
#pragma unroll
                for (int r = 0; r < 4; ++r) {
                    float u = fmaxf(C[mt][r] * rs - mrs, 0.f);
                    accf[mt][r] += u;
                    accb[mt][r] += u;
                }
        } else {
#pragma unroll
            for (int mt = 0; mt < 4; ++mt)
#pragma unroll
                for (int r = 0; r < 4; ++r)
                    accf[mt][r] += fmaxf(C[mt][r] * rs - mrs, 0.f);
            float de = (float)((sb >> l15) & 1u) - ef;
            float t1 = 0.f, t2 = 0.f;
#pragma unroll
            for (int mt = 0; mt < 4; ++mt)
#pragma unroll
                for (int r = 0; r < 4; ++r) {
                    float v = C[mt][r] + de * hww[mt][r];
                    C[mt][r] = v;
                    t1 += v;
                    t2 += v * v;
                }
            t1 += __shfl_xor(t1, 16); t1 += __shfl_xor(t1, 32);
            t2 += __shfl_xor(t2, 16); t2 += __shfl_xor(t2, 32);
            float mean2 = t1 * (1.f / DD);
            float var2 = fmaxf(t2 * (1.f / DD) - mean2 * mean2, 0.f);
            float rs2 = rsqrtf(var2 + EPSF);
            float mrs2 = mean2 * rs2;
#pragma unroll
            for (int mt = 0; mt < 4; ++mt)
#pragma unroll
                for (int r = 0; r < 4; ++r)
                    accb[mt][r] += fmaxf(C[mt][r] * rs2 - mrs2, 0.f);
        }
    }

#pragma unroll
    for (int step = 1; step < 16; step <<= 1)
#pragma unroll
        for (int mt = 0; mt < 4; ++mt)
#pragma unroll
            for (int r = 0; r < 4; ++r) {
                accf[mt][r] += __shfl_xor(accf[mt][r], step);
                accb[mt][r] += __shfl_xor(accb[mt][r], step);
            }
    if (l15 == 0) {
#pragma unroll
        for (int mt = 0; mt < 4; ++mt)
#pragma unroll
            for (int r = 0; r < 4; ++r) {
                int m = mt * 16 + quad * 4 + r;
                red[wave * 128 + m] = accf[mt][r];
                red[wave * 128 + DD + m] = accb[mt][r];
            }
    }
    __syncthreads();
    // combine wave partials into red[0..127] = {vec_p(b), vec_q(b)}
    if (tid < 128) {
        float sum = red[tid] + red[128 + tid] + red[256 + tid] + red[384 + tid];
        red[tid] = sum;
    }
    __syncthreads();
    // fused projection: ppb = vec_p @ g_W[65:129], qqb = vec_q @ g_W[129:193]
    if (wave < 2) {
        const float* sv = red + wave * DD;
        int row0 = wave ? 129 : 65;
        float o = 0.f;
        for (int k = 0; k < DD; ++k) o += sv[k] * gWf[(row0 + k) * DD + lane];
        (wave ? qqb : ppb)[b * DD + lane] = o;
    }
}

// =============== K5: final selected pairs (MFMA) ===============
__global__ __launch_bounds__(256) void k_final(
        const void* __restrict__ emb,
        const int* __restrict__ pos, const unsigned short* __restrict__ hbf,
        const float* __restrict__ gWf, const unsigned int* __restrict__ eim,
        const float* __restrict__ ppb, const float* __restrict__ qqb,
        const float* __restrict__ linf, void* __restrict__ outv) {
    __shared__ __align__(16) unsigned short sgW[DD * SWP];
    const int b = blockIdx.x, tid = threadIdx.x;
    const int lane = tid & 63, wave = tid >> 6;
    const int l15 = lane & 15, quad = lane >> 4;
    const int fl = probe_fl(emb);

    {
        int m = tid >> 2;
        int k0 = (tid & 3) * 16;
        unsigned short tmp[16];
#pragma unroll
        for (int u = 0; u < 16; ++u) tmp[u] = f2bf_u(gWf[(k0 + u) * DD + m]);
        *(short8*)(sgW + m * SWP + k0) = *(short8*)tmp;
        *(short8*)(sgW + m * SWP + k0 + 8) = *(short8*)(tmp + 8);
    }

    int pp_ = b * 64 + wave * 16 + l15;
    int a = pos[2 * pp_], bb = pos[2 * pp_ + 1];
    short8 ha0 = *(const short8*)(hbf + a * DD + quad * 8);
    short8 hb0v = *(const short8*)(hbf + bb * DD + quad * 8);
    short8 ha1 = *(const short8*)(hbf + a * DD + 32 + quad * 8);
    short8 hb1v = *(const short8*)(hbf + bb * DD + 32 + quad * 8);
    short8 B0, B1;
#pragma unroll
    for (int j = 0; j < 8; ++j) {
        B0[j] = (short)f2bf_u(bfu2f((unsigned short)ha0[j]) * bfu2f((unsigned short)hb0v[j]));
        B1[j] = (short)f2bf_u(bfu2f((unsigned short)ha1[j]) * bfu2f((unsigned short)hb1v[j]));
    }
    __syncthreads();

    f32x4 C[4];
#pragma unroll
    for (int mt = 0; mt < 4; ++mt) C[mt] = (f32x4){0.f, 0.f, 0.f, 0.f};
#pragma unroll
    for (int mt = 0; mt < 4; ++mt) {
        short8 A0 = *(const short8*)(sgW + (mt * 16 + l15) * SWP + quad * 8);
        C[mt] = __builtin_amdgcn_mfma_f32_16x16x32_bf16(A0, B0, C[mt], 0, 0, 0);
    }
#pragma unroll
    for (int mt = 0; mt < 4; ++mt) {
        short8 A1 = *(const short8*)(sgW + (mt * 16 + l15) * SWP + 32 + quad * 8);
        C[mt] = __builtin_amdgcn_mfma_f32_16x16x32_bf16(A1, B1, C[mt], 0, 0, 0);
    }

    unsigned int iab = (unsigned int)(a * NN + bb), iba = (unsigned int)(bb * NN + a);
    float eab = (float)((eim[iab >> 5] >> (iab & 31)) & 1u);
    float eba = (float)((eim[iba >> 5] >> (iba & 31)) & 1u);

    float u1[4][4], u2[4][4];
    float s1 = 0.f, s12 = 0.f, s2 = 0.f, s22 = 0.f;
#pragma unroll
    for (int mt = 0; mt < 4; ++mt) {
        int m0 = mt * 16 + quad * 4;
        f32x4 w64v = *(const f32x4*)(gWf + 64 * DD + m0);
        f32x4 gbv  = *(const f32x4*)(gWf + 193 * DD + m0);
        f32x4 ppa  = *(const f32x4*)(ppb + a * DD + m0);
        f32x4 qqb_ = *(const f32x4*)(qqb + bb * DD + m0);
        f32x4 ppb_ = *(const f32x4*)(ppb + bb * DD + m0);
        f32x4 qqa  = *(const f32x4*)(qqb + a * DD + m0);
#pragma unroll
        for (int r = 0; r < 4; ++r) {
            float v1 = C[mt][r] + eab * w64v[r] + ppa[r] + qqb_[r] + gbv[r];
            float v2 = C[mt][r] + eba * w64v[r] + ppb_[r] + qqa[r] + gbv[r];
            u1[mt][r] = v1; u2[mt][r] = v2;
            s1 += v1; s12 += v1 * v1;
            s2 += v2; s22 += v2 * v2;
        }
    }
    s1 += __shfl_xor(s1, 16);  s1 += __shfl_xor(s1, 32);
    s12 += __shfl_xor(s12, 16); s12 += __shfl_xor(s12, 32);
    s2 += __shfl_xor(s2, 16);  s2 += __shfl_xor(s2, 32);
    s22 += __shfl_xor(s22, 16); s22 += __shfl_xor(s22, 32);
    float mean1 = s1 * (1.f / DD);
    float rs1 = rsqrtf(fmaxf(s12 * (1.f / DD) - mean1 * mean1, 0.f) + EPSF);
    float mrs1 = mean1 * rs1;
    float mean2 = s2 * (1.f / DD);
    float rs2 = rsqrtf(fmaxf(s22 * (1.f / DD) - mean2 * mean2, 0.f) + EPSF);
    float mrs2 = mean2 * rs2;

    float r = 0.f;
#pragma unroll
    for (int mt = 0; mt < 4; ++mt) {
        f32x4 lw = *(const f32x4*)(linf + mt * 16 + quad * 4);
#pragma unroll
        for (int rr = 0; rr < 4; ++rr) {
            float g1 = fmaxf(u1[mt][rr] * rs1 - mrs1, 0.f);
            float g2 = fmaxf(u2[mt][rr] * rs2 - mrs2, 0.f);
            r += g1 * g2 * lw[rr];
        }
    }
    r += __shfl_xor(r, 16); r += __shfl_xor(r, 32);
    if (quad == 0) {
        float res = r + linf[DD];
        if (fl) ((float*)outv)[pp_] = res;
        else    ((bf16*)outv)[pp_] = __float2bfloat16(res);
    }
}

extern "C" void kernel_launch(void* const* d_in, const int* in_sizes, int n_in,
                              void* d_out, int out_size, void* d_ws, size_t ws_size,
                              hipStream_t stream) {
    const int* x   = (const int*)d_in[0];
    const int* ei  = (const int*)d_in[1];
    const int* pos = (const int*)d_in[2];
    const void* emb = d_in[3];

    char* w = (char*)d_ws;
    auto alloc = [&](size_t bytes) {
        void* q = (void*)w;
        w += (bytes + 255) & ~(size_t)255;
        return q;
    };
    unsigned int* eim  = (unsigned int*)alloc(NN * NN / 8);
    unsigned int* eimT = (unsigned int*)alloc(NN * NN / 8);
    float* h0   = (float*)alloc(NN * DD * 4);
    float* h1   = (float*)alloc(NN * DD * 4);
    float* h2   = (float*)alloc(NN * DD * 4);
    unsigned short* hbf = (unsigned short*)alloc(NN * DD * 2);
    float* Wlf  = (float*)alloc(2 * DD * DD * 4);
    float* blf  = (float*)alloc(2 * DD * 4);
    float* Wrf  = (float*)alloc(2 * DD * DD * 4);
    float* WfT  = (float*)alloc(DD * DD * 4);
    float* hbw  = (float*)alloc(128 * 4);
    float* gWf  = (float*)alloc(194 * DD * 4);
    float* linf = (float*)alloc(65 * 4);
    float* ppb  = (float*)alloc(NN * DD * 4);
    float* qqb  = (float*)alloc(NN * DD * 4);
    int* rowptr = (int*)alloc((NN + 1) * 4);
    int* csrc   = (int*)alloc(EE * 4);

    k_prep<<<389, 256, 0, stream>>>(emb, d_in[4], d_in[5], d_in[6], d_in[7], d_in[8],
                                    d_in[9], d_in[10], d_in[11], d_in[12],
                                    x, ei, Wlf, blf, Wrf, WfT, hbw, gWf, linf,
                                    h0, eim, eimT, rowptr, csrc);
    k_sage0<<<256, 256, 0, stream>>>(ei, rowptr, csrc, h0, Wlf, blf, Wrf, h1, eim, eimT);
    k_sage1<<<256, 256, 0, stream>>>(rowptr, csrc, h1, Wlf, blf, Wrf, h2, hbf);
    k_bstage<<<NN, 256, 0, stream>>>(h2, hbf, WfT, hbw, eim, eimT, gWf, ppb, qqb);
    k_final<<<PP / 64, 256, 0, stream>>>(emb, pos, hbf, gWf, eim, ppb, qqb, linf, d_out);
}

// Round 9
// 192.827 us; speedup vs baseline: 1.4269x; 1.4269x over previous
//
#include <hip/hip_runtime.h>
#include <hip/hip_bf16.h>

#define NN 1024
#define DD 64
#define EE 16384
#define PP 8192
#define EPSF 1e-5f
#define SWP (DD + 8)   // padded LDS row stride in shorts (144 B)

typedef __hip_bfloat16 bf16;
typedef __attribute__((ext_vector_type(8))) short short8;
typedef __attribute__((ext_vector_type(4))) float f32x4;

static __device__ __forceinline__ float dec1(const void* src, int i, int fl) {
    if (fl) return ((const float*)src)[i];
    return __bfloat162float(((const bf16*)src)[i]);
}
static __device__ __forceinline__ unsigned short f2bf_u(float f) {
    bf16 h = __float2bfloat16(f);
    return *reinterpret_cast<unsigned short*>(&h);
}
static __device__ __forceinline__ float bfu2f(unsigned short u) {
    return __uint_as_float(((unsigned int)u) << 16);
}
static __device__ __forceinline__ int probe_fl(const void* emb) {
    int lane = threadIdx.x & 63;
    unsigned short raw = ((const unsigned short*)emb)[lane];
    float v = __uint_as_float(((unsigned int)raw) << 16);
    return (__ballot(!(fabsf(v) <= 1e3f)) != 0ull) ? 1 : 0;
}

// =============== K1: decode everything + embed + zero bitmaps + CSR build ===============
__global__ __launch_bounds__(256) void k_prep(
        const void* __restrict__ emb, const void* __restrict__ sWl,
        const void* __restrict__ sbl, const void* __restrict__ sWr,
        const void* __restrict__ hW, const void* __restrict__ hb,
        const void* __restrict__ gW, const void* __restrict__ gb,
        const void* __restrict__ lW, const void* __restrict__ lb,
        const int* __restrict__ x, const int* __restrict__ ei,
        float* __restrict__ Wlf, float* __restrict__ blf, float* __restrict__ Wrf,
        float* __restrict__ WfT, float* __restrict__ hbw,
        float* __restrict__ gWf, float* __restrict__ linf,
        float* __restrict__ h0,
        unsigned int* __restrict__ eim, unsigned int* __restrict__ eimT,
        int* __restrict__ rowptr, int* __restrict__ csrc) {
    __shared__ int sdeg[NN];
    __shared__ int stmp[256];
    const int b = blockIdx.x, tid = threadIdx.x;
    const int fl = probe_fl(emb);

    // zero the edge bitmaps (65536 words over blocks 0..255)
    if (b < 256) {
        int z = b * 256 + tid;
        if (z < 32768) eim[z] = 0u;
        else           eimT[z - 32768] = 0u;
    }

    if (b < 32) { int i = b * 256 + tid; Wlf[i] = dec1(sWl, i, fl); }
    else if (b == 32) { if (tid < 128) blf[tid] = dec1(sbl, tid, fl); }
    else if (b < 65) { int i = (b - 33) * 256 + tid; Wrf[i] = dec1(sWr, i, fl); }
    else if (b < 82) {
        int i = (b - 65) * 256 + tid;
        if (i < 4096) { int n = i >> 6, k = i & 63; WfT[n * DD + k] = dec1(hW, k * DD + n, fl); }
        else if (i < 4160) hbw[i - 4096] = dec1(hb, i - 4096, fl);
        else if (i < 4224) hbw[64 + (i - 4160)] = dec1(hW, 64 * DD + (i - 4160), fl);
    } else if (b < 131) {
        int i = (b - 82) * 256 + tid;
        if (i < 193 * DD) gWf[i] = dec1(gW, i, fl);
        else if (i < 194 * DD) gWf[i] = dec1(gb, i - 193 * DD, fl);
    } else if (b == 131) {
        if (tid < DD) linf[tid] = dec1(lW, tid, fl);
        else if (tid == DD) linf[DD] = dec1(lb, 0, fl);
    } else if (b < 388) {
        int i = (b - 132) * 256 + tid;
        int node = i >> 6, f = i & 63;
        h0[i] = dec1(emb, x[node] * DD + f, fl);
    } else if (b == 388) {
        // ---- CSR build, single block ----
        for (int i = tid; i < NN; i += 256) sdeg[i] = 0;
        __syncthreads();
        for (int e = tid; e < EE; e += 256) atomicAdd(&sdeg[ei[EE + e]], 1);
        __syncthreads();
        int base4 = tid * 4;
        int v[4]; int s = 0;
#pragma unroll
        for (int u = 0; u < 4; ++u) { v[u] = sdeg[base4 + u]; s += v[u]; }
        stmp[tid] = s;
        __syncthreads();
        for (int off = 1; off < 256; off <<= 1) {
            int a = (tid >= off) ? stmp[tid - off] : 0;
            __syncthreads();
            stmp[tid] += a;
            __syncthreads();
        }
        int run = stmp[tid] - s;
#pragma unroll
        for (int u = 0; u < 4; ++u) {
            rowptr[base4 + u] = run;
            sdeg[base4 + u] = run;    // becomes cursor
            run += v[u];
        }
        if (tid == 255) rowptr[NN] = run;
        __syncthreads();
        for (int e = tid; e < EE; e += 256) {
            int d = ei[EE + e];
            int c = atomicAdd(&sdeg[d], 1);
            csrc[c] = ei[e];
        }
    }
}

// =============== shared SAGE body (one wave per node) ===============
static __device__ __forceinline__ void sage_body(
        char* smem, int node, int lane, int wave,
        const int* __restrict__ rowptr, const int* __restrict__ csrc,
        const float* __restrict__ hin,
        const float* __restrict__ Wl, const float* __restrict__ bl,
        const float* __restrict__ Wr,
        float* __restrict__ hout, unsigned short* __restrict__ hbf) {
    float* sa = (float*)smem + wave * 2 * DD;
    float* sh = sa + DD;
    int r0 = rowptr[node], r1 = rowptr[node + 1];
    float s = 0.f;
    for (int r = r0; r < r1; ++r) s += hin[csrc[r] * DD + lane];
    sa[lane] = s / (float)max(r1 - r0, 1);
    sh[lane] = hin[node * DD + lane];
    float o = bl[lane];
    for (int k = 0; k < DD; ++k)
        o += sa[k] * Wl[k * DD + lane] + sh[k] * Wr[k * DD + lane];
    float m = o;
    for (int off = 32; off; off >>= 1) m += __shfl_xor(m, off);
    m *= (1.f / DD);
    float d0 = o - m;
    float v = d0 * d0;
    for (int off = 32; off; off >>= 1) v += __shfl_xor(v, off);
    v *= (1.f / DD);
    float r = d0 * rsqrtf(v + EPSF);
    hout[node * DD + lane] = r;
    if (hbf) hbf[node * DD + lane] = f2bf_u(r);
}

// =============== K2: SAGE round 0 + edge-bitmap atomics ===============
__global__ __launch_bounds__(256) void k_sage0(
        const int* __restrict__ ei,
        const int* __restrict__ rowptr, const int* __restrict__ csrc,
        const float* __restrict__ h0,
        const float* __restrict__ Wlf, const float* __restrict__ blf,
        const float* __restrict__ Wrf,
        float* __restrict__ h1,
        unsigned int* __restrict__ eim, unsigned int* __restrict__ eimT) {
    __shared__ __align__(16) char smem[4 * 2 * DD * 4];
    const int b = blockIdx.x, tid = threadIdx.x;
    const int lane = tid & 63, wave = tid >> 6;
    if (tid < 64) {
        int e = b * 64 + tid;
        int s = ei[e], d = ei[EE + e];
        unsigned int idx = (unsigned int)(s * NN + d);
        atomicOr(&eim[idx >> 5], 1u << (idx & 31));
        unsigned int idxT = (unsigned int)(d * NN + s);
        atomicOr(&eimT[idxT >> 5], 1u << (idxT & 31));
    }
    sage_body(smem, b * 4 + wave, lane, wave, rowptr, csrc, h0, Wlf, blf, Wrf,
              h1, (unsigned short*)nullptr);
}

// =============== K3: SAGE round 1 (writes h2 + bf16 copy) ===============
__global__ __launch_bounds__(256) void k_sage1(
        const int* __restrict__ rowptr, const int* __restrict__ csrc,
        const float* __restrict__ h1,
        const float* __restrict__ Wlf, const float* __restrict__ blf,
        const float* __restrict__ Wrf,
        float* __restrict__ h2, unsigned short* __restrict__ hbf) {
    __shared__ __align__(16) char smem[4 * 2 * DD * 4];
    const int b = blockIdx.x, tid = threadIdx.x;
    const int lane = tid & 63, wave = tid >> 6;
    sage_body(smem, b * 4 + wave, lane, wave, rowptr, csrc, h1,
              Wlf + DD * DD, blf + DD, Wrf + DD * DD, h2, hbf);
}

// =============== K4: B-stage (MFMA) + fused pp/qq projection ===============
// NOTE: plain __launch_bounds__(256) — a (256,4) min-waves spec capped VGPR at 64
// and spilled ~100 live values to scratch (R8: WRITE 52 MB, FETCH 373 MB, 2.4x slower).
__global__ __launch_bounds__(256) void k_bstage(
        const float* __restrict__ h2, const unsigned short* __restrict__ hbf,
        const float* __restrict__ WfT, const float* __restrict__ hbw,
        const unsigned int* __restrict__ eim, const unsigned int* __restrict__ eimT,
        const float* __restrict__ gWf,
        float* __restrict__ ppb, float* __restrict__ qqb) {
    __shared__ __align__(16) unsigned short sW[DD * SWP];  // 9216 B
    __shared__ __align__(16) float red[4 * 128];           // 2048 B
    const int b = blockIdx.x, tid = threadIdx.x;
    const int lane = tid & 63, wave = tid >> 6;
    const int l15 = lane & 15, quad = lane >> 4;

    {
        int m = tid >> 2;
        int k0 = (tid & 3) * 16;
        const float* hi = h2 + b * DD;
        const float* wr = WfT + m * DD;
        unsigned short tmp[16];
#pragma unroll
        for (int u = 0; u < 16; ++u) tmp[u] = f2bf_u(hi[k0 + u] * wr[k0 + u]);
        *(short8*)(sW + m * SWP + k0) = *(short8*)tmp;
        *(short8*)(sW + m * SWP + k0 + 8) = *(short8*)(tmp + 8);
    }
    __syncthreads();

    short8 Af[4][2];
#pragma unroll
    for (int mt = 0; mt < 4; ++mt)
#pragma unroll
        for (int kt = 0; kt < 2; ++kt)
            Af[mt][kt] = *(const short8*)(sW + (mt * 16 + l15) * SWP + kt * 32 + quad * 8);

    float hb0[4][4], hww[4][4];
#pragma unroll
    for (int mt = 0; mt < 4; ++mt) {
        f32x4 a = *(const f32x4*)(hbw + mt * 16 + quad * 4);
        f32x4 wv = *(const f32x4*)(hbw + 64 + mt * 16 + quad * 4);
#pragma unroll
        for (int r = 0; r < 4; ++r) { hb0[mt][r] = a[r]; hww[mt][r] = wv[r]; }
    }

    float accf[4][4], accb[4][4];
#pragma unroll
    for (int mt = 0; mt < 4; ++mt)
#pragma unroll
        for (int r = 0; r < 4; ++r) { accf[mt][r] = 0.f; accb[mt][r] = 0.f; }

    int g = wave;
    short8 B0 = *(const short8*)(hbf + (g * 16 + l15) * DD + quad * 8);
    short8 B1 = *(const short8*)(hbf + (g * 16 + l15) * DD + 32 + quad * 8);

    for (int it = 0; it < 16; ++it, g += 4) {
        short8 cB0 = B0, cB1 = B1;
        if (it < 15) {
            int gn = g + 4;
            B0 = *(const short8*)(hbf + (gn * 16 + l15) * DD + quad * 8);
            B1 = *(const short8*)(hbf + (gn * 16 + l15) * DD + 32 + quad * 8);
        }
        unsigned int base = (unsigned int)(b * NN + g * 16);
        unsigned int sf = (eim[base >> 5] >> (base & 31)) & 0xFFFFu;
        unsigned int sb = (eimT[base >> 5] >> (base & 31)) & 0xFFFFu;

        f32x4 C[4];
#pragma unroll
        for (int mt = 0; mt < 4; ++mt)
            C[mt] = (f32x4){hb0[mt][0], hb0[mt][1], hb0[mt][2], hb0[mt][3]};
#pragma unroll
        for (int mt = 0; mt < 4; ++mt)
            C[mt] = __builtin_amdgcn_mfma_f32_16x16x32_bf16(Af[mt][0], cB0, C[mt], 0, 0, 0);
#pragma unroll
        for (int mt = 0; mt < 4; ++mt)
            C[mt] = __builtin_amdgcn_mfma_f32_16x16x32_bf16(Af[mt][1], cB1, C[mt], 0, 0, 0);

        float ef = (float)((sf >> l15) & 1u);
        float s1 = 0.f, s2 = 0.f;
#pragma unroll
        for (int mt = 0; mt < 4; ++mt)
#pragma unroll
            for (int r = 0; r < 4; ++r) {
                float v = C[mt][r] + ef * hww[mt][r];
                C[mt][r] = v;
                s1 += v;
                s2 += v * v;
            }
        s1 += __shfl_xor(s1, 16); s1 += __shfl_xor(s1, 32);
        s2 += __shfl_xor(s2, 16); s2 += __shfl_xor(s2, 32);
        float mean = s1 * (1.f / DD);
        float var = fmaxf(s2 * (1.f / DD) - mean * mean, 0.f);
        float rs = rsqrtf(var + EPSF);
        float mrs = mean * rs;

        if (sf == sb) {
#pragma unroll
            for (int mt = 0; mt < 4; ++mt)
#pragma unroll
                for (int r = 0; r < 4; ++r) {
                    float u = fmaxf(C[mt][r] * rs - mrs, 0.f);
                    accf[mt][r] += u;
                    accb[mt][r] += u;
                }
        } else {
#pragma unroll
            for (int mt = 0; mt < 4; ++mt)
#pragma unroll
                for (int r = 0; r < 4; ++r)
                    accf[mt][r] += fmaxf(C[mt][r] * rs - mrs, 0.f);
            float de = (float)((sb >> l15) & 1u) - ef;
            float t1 = 0.f, t2 = 0.f;
#pragma unroll
            for (int mt = 0; mt < 4; ++mt)
#pragma unroll
                for (int r = 0; r < 4; ++r) {
                    float v = C[mt][r] + de * hww[mt][r];
                    C[mt][r] = v;
                    t1 += v;
                    t2 += v * v;
                }
            t1 += __shfl_xor(t1, 16); t1 += __shfl_xor(t1, 32);
            t2 += __shfl_xor(t2, 16); t2 += __shfl_xor(t2, 32);
            float mean2 = t1 * (1.f / DD);
            float var2 = fmaxf(t2 * (1.f / DD) - mean2 * mean2, 0.f);
            float rs2 = rsqrtf(var2 + EPSF);
            float mrs2 = mean2 * rs2;
#pragma unroll
            for (int mt = 0; mt < 4; ++mt)
#pragma unroll
                for (int r = 0; r < 4; ++r)
                    accb[mt][r] += fmaxf(C[mt][r] * rs2 - mrs2, 0.f);
        }
    }

#pragma unroll
    for (int step = 1; step < 16; step <<= 1)
#pragma unroll
        for (int mt = 0; mt < 4; ++mt)
#pragma unroll
            for (int r = 0; r < 4; ++r) {
                accf[mt][r] += __shfl_xor(accf[mt][r], step);
                accb[mt][r] += __shfl_xor(accb[mt][r], step);
            }
    if (l15 == 0) {
#pragma unroll
        for (int mt = 0; mt < 4; ++mt)
#pragma unroll
            for (int r = 0; r < 4; ++r) {
                int m = mt * 16 + quad * 4 + r;
                red[wave * 128 + m] = accf[mt][r];
                red[wave * 128 + DD + m] = accb[mt][r];
            }
    }
    __syncthreads();
    // combine wave partials into red[0..127] = {vec_p(b), vec_q(b)}
    if (tid < 128) {
        float sum = red[tid] + red[128 + tid] + red[256 + tid] + red[384 + tid];
        red[tid] = sum;
    }
    __syncthreads();
    // fused projection: ppb = vec_p @ g_W[65:129], qqb = vec_q @ g_W[129:193]
    if (wave < 2) {
        const float* sv = red + wave * DD;
        int row0 = wave ? 129 : 65;
        float o = 0.f;
        for (int k = 0; k < DD; ++k) o += sv[k] * gWf[(row0 + k) * DD + lane];
        (wave ? qqb : ppb)[b * DD + lane] = o;
    }
}

// =============== K5: final selected pairs (MFMA) ===============
__global__ __launch_bounds__(256) void k_final(
        const void* __restrict__ emb,
        const int* __restrict__ pos, const unsigned short* __restrict__ hbf,
        const float* __restrict__ gWf, const unsigned int* __restrict__ eim,
        const float* __restrict__ ppb, const float* __restrict__ qqb,
        const float* __restrict__ linf, void* __restrict__ outv) {
    __shared__ __align__(16) unsigned short sgW[DD * SWP];
    const int b = blockIdx.x, tid = threadIdx.x;
    const int lane = tid & 63, wave = tid >> 6;
    const int l15 = lane & 15, quad = lane >> 4;
    const int fl = probe_fl(emb);

    {
        int m = tid >> 2;
        int k0 = (tid & 3) * 16;
        unsigned short tmp[16];
#pragma unroll
        for (int u = 0; u < 16; ++u) tmp[u] = f2bf_u(gWf[(k0 + u) * DD + m]);
        *(short8*)(sgW + m * SWP + k0) = *(short8*)tmp;
        *(short8*)(sgW + m * SWP + k0 + 8) = *(short8*)(tmp + 8);
    }

    int pp_ = b * 64 + wave * 16 + l15;
    int a = pos[2 * pp_], bb = pos[2 * pp_ + 1];
    short8 ha0 = *(const short8*)(hbf + a * DD + quad * 8);
    short8 hb0v = *(const short8*)(hbf + bb * DD + quad * 8);
    short8 ha1 = *(const short8*)(hbf + a * DD + 32 + quad * 8);
    short8 hb1v = *(const short8*)(hbf + bb * DD + 32 + quad * 8);
    short8 B0, B1;
#pragma unroll
    for (int j = 0; j < 8; ++j) {
        B0[j] = (short)f2bf_u(bfu2f((unsigned short)ha0[j]) * bfu2f((unsigned short)hb0v[j]));
        B1[j] = (short)f2bf_u(bfu2f((unsigned short)ha1[j]) * bfu2f((unsigned short)hb1v[j]));
    }
    __syncthreads();

    f32x4 C[4];
#pragma unroll
    for (int mt = 0; mt < 4; ++mt) C[mt] = (f32x4){0.f, 0.f, 0.f, 0.f};
#pragma unroll
    for (int mt = 0; mt < 4; ++mt) {
        short8 A0 = *(const short8*)(sgW + (mt * 16 + l15) * SWP + quad * 8);
        C[mt] = __builtin_amdgcn_mfma_f32_16x16x32_bf16(A0, B0, C[mt], 0, 0, 0);
    }
#pragma unroll
    for (int mt = 0; mt < 4; ++mt) {
        short8 A1 = *(const short8*)(sgW + (mt * 16 + l15) * SWP + 32 + quad * 8);
        C[mt] = __builtin_amdgcn_mfma_f32_16x16x32_bf16(A1, B1, C[mt], 0, 0, 0);
    }

    unsigned int iab = (unsigned int)(a * NN + bb), iba = (unsigned int)(bb * NN + a);
    float eab = (float)((eim[iab >> 5] >> (iab & 31)) & 1u);
    float eba = (float)((eim[iba >> 5] >> (iba & 31)) & 1u);

    float u1[4][4], u2[4][4];
    float s1 = 0.f, s12 = 0.f, s2 = 0.f, s22 = 0.f;
#pragma unroll
    for (int mt = 0; mt < 4; ++mt) {
        int m0 = mt * 16 + quad * 4;
        f32x4 w64v = *(const f32x4*)(gWf + 64 * DD + m0);
        f32x4 gbv  = *(const f32x4*)(gWf + 193 * DD + m0);
        f32x4 ppa  = *(const f32x4*)(ppb + a * DD + m0);
        f32x4 qqb_ = *(const f32x4*)(qqb + bb * DD + m0);
        f32x4 ppb_ = *(const f32x4*)(ppb + bb * DD + m0);
        f32x4 qqa  = *(const f32x4*)(qqb + a * DD + m0);
#pragma unroll
        for (int r = 0; r < 4; ++r) {
            float v1 = C[mt][r] + eab * w64v[r] + ppa[r] + qqb_[r] + gbv[r];
            float v2 = C[mt][r] + eba * w64v[r] + ppb_[r] + qqa[r] + gbv[r];
            u1[mt][r] = v1; u2[mt][r] = v2;
            s1 += v1; s12 += v1 * v1;
            s2 += v2; s22 += v2 * v2;
        }
    }
    s1 += __shfl_xor(s1, 16);  s1 += __shfl_xor(s1, 32);
    s12 += __shfl_xor(s12, 16); s12 += __shfl_xor(s12, 32);
    s2 += __shfl_xor(s2, 16);  s2 += __shfl_xor(s2, 32);
    s22 += __shfl_xor(s22, 16); s22 += __shfl_xor(s22, 32);
    float mean1 = s1 * (1.f / DD);
    float rs1 = rsqrtf(fmaxf(s12 * (1.f / DD) - mean1 * mean1, 0.f) + EPSF);
    float mrs1 = mean1 * rs1;
    float mean2 = s2 * (1.f / DD);
    float rs2 = rsqrtf(fmaxf(s22 * (1.f / DD) - mean2 * mean2, 0.f) + EPSF);
    float mrs2 = mean2 * rs2;

    float r = 0.f;
#pragma unroll
    for (int mt = 0; mt < 4; ++mt) {
        f32x4 lw = *(const f32x4*)(linf + mt * 16 + quad * 4);
#pragma unroll
        for (int rr = 0; rr < 4; ++rr) {
            float g1 = fmaxf(u1[mt][rr] * rs1 - mrs1, 0.f);
            float g2 = fmaxf(u2[mt][rr] * rs2 - mrs2, 0.f);
            r += g1 * g2 * lw[rr];
        }
    }
    r += __shfl_xor(r, 16); r += __shfl_xor(r, 32);
    if (quad == 0) {
        float res = r + linf[DD];
        if (fl) ((float*)outv)[pp_] = res;
        else    ((bf16*)outv)[pp_] = __float2bfloat16(res);
    }
}

extern "C" void kernel_launch(void* const* d_in, const int* in_sizes, int n_in,
                              void* d_out, int out_size, void* d_ws, size_t ws_size,
                              hipStream_t stream) {
    const int* x   = (const int*)d_in[0];
    const int* ei  = (const int*)d_in[1];
    const int* pos = (const int*)d_in[2];
    const void* emb = d_in[3];

    char* w = (char*)d_ws;
    auto alloc = [&](size_t bytes) {
        void* q = (void*)w;
        w += (bytes + 255) & ~(size_t)255;
        return q;
    };
    unsigned int* eim  = (unsigned int*)alloc(NN * NN / 8);
    unsigned int* eimT = (unsigned int*)alloc(NN * NN / 8);
    float* h0   = (float*)alloc(NN * DD * 4);
    float* h1   = (float*)alloc(NN * DD * 4);
    float* h2   = (float*)alloc(NN * DD * 4);
    unsigned short* hbf = (unsigned short*)alloc(NN * DD * 2);
    float* Wlf  = (float*)alloc(2 * DD * DD * 4);
    float* blf  = (float*)alloc(2 * DD * 4);
    float* Wrf  = (float*)alloc(2 * DD * DD * 4);
    float* WfT  = (float*)alloc(DD * DD * 4);
    float* hbw  = (float*)alloc(128 * 4);
    float* gWf  = (float*)alloc(194 * DD * 4);
    float* linf = (float*)alloc(65 * 4);
    float* ppb  = (float*)alloc(NN * DD * 4);
    float* qqb  = (float*)alloc(NN * DD * 4);
    int* rowptr = (int*)alloc((NN + 1) * 4);
    int* csrc   = (int*)alloc(EE * 4);

    k_prep<<<389, 256, 0, stream>>>(emb, d_in[4], d_in[5], d_in[6], d_in[7], d_in[8],
                                    d_in[9], d_in[10], d_in[11], d_in[12],
                                    x, ei, Wlf, blf, Wrf, WfT, hbw, gWf, linf,
                                    h0, eim, eimT, rowptr, csrc);
    k_sage0<<<256, 256, 0, stream>>>(ei, rowptr, csrc, h0, Wlf, blf, Wrf, h1, eim, eimT);
    k_sage1<<<256, 256, 0, stream>>>(rowptr, csrc, h1, Wlf, blf, Wrf, h2, hbf);
    k_bstage<<<NN, 256, 0, stream>>>(h2, hbf, WfT, hbw, eim, eimT, gWf, ppb, qqb);
    k_final<<<PP / 64, 256, 0, stream>>>(emb, pos, hbf, gWf, eim, ppb, qqb, linf, d_out);
}

// Round 10
// 161.615 us; speedup vs baseline: 1.7024x; 1.1931x over previous
//
#include <hip/hip_runtime.h>
#include <hip/hip_bf16.h>

#define NN 1024
#define DD 64
#define EE 16384
#define PP 8192
#define EPSF 1e-5f
#define SWP (DD + 8)   // padded LDS row stride in shorts (144 B)

typedef __hip_bfloat16 bf16;
typedef __attribute__((ext_vector_type(8))) short short8;
typedef __attribute__((ext_vector_type(4))) float f32x4;

static __device__ __forceinline__ float dec1(const void* src, int i, int fl) {
    if (fl) return ((const float*)src)[i];
    return __bfloat162float(((const bf16*)src)[i]);
}
static __device__ __forceinline__ unsigned short f2bf_u(float f) {
    bf16 h = __float2bfloat16(f);
    return *reinterpret_cast<unsigned short*>(&h);
}
static __device__ __forceinline__ float bfu2f(unsigned short u) {
    return __uint_as_float(((unsigned int)u) << 16);
}
static __device__ __forceinline__ int probe_fl(const void* emb) {
    int lane = threadIdx.x & 63;
    unsigned short raw = ((const unsigned short*)emb)[lane];
    float v = __uint_as_float(((unsigned int)raw) << 16);
    return (__ballot(!(fabsf(v) <= 1e3f)) != 0ull) ? 1 : 0;
}

// =============== K1: decode everything + embed + zero bitmaps + CSR build ===============
// CSR block uses explicit 8/16-wide register batching: R9 showed VGPR_Count=8 —
// the allocator serialized the edge loops into back-to-back ~900-cyc HBM round
// trips (60-80 us). Batching forces registers and keeps 8-16 loads in flight.
__global__ __launch_bounds__(256) void k_prep(
        const void* __restrict__ emb, const void* __restrict__ sWl,
        const void* __restrict__ sbl, const void* __restrict__ sWr,
        const void* __restrict__ hW, const void* __restrict__ hb,
        const void* __restrict__ gW, const void* __restrict__ gb,
        const void* __restrict__ lW, const void* __restrict__ lb,
        const int* __restrict__ x, const int* __restrict__ ei,
        float* __restrict__ Wlf, float* __restrict__ blf, float* __restrict__ Wrf,
        float* __restrict__ WfT, float* __restrict__ hbw,
        float* __restrict__ gWf, float* __restrict__ linf,
        float* __restrict__ h0,
        unsigned int* __restrict__ eim, unsigned int* __restrict__ eimT,
        int* __restrict__ rowptr, int* __restrict__ csrc) {
    __shared__ int sdeg[NN];
    __shared__ int stmp[256];
    const int b = blockIdx.x, tid = threadIdx.x;
    const int fl = probe_fl(emb);

    // zero the edge bitmaps (65536 words over blocks 0..255)
    if (b < 256) {
        int z = b * 256 + tid;
        if (z < 32768) eim[z] = 0u;
        else           eimT[z - 32768] = 0u;
    }

    if (b < 32) { int i = b * 256 + tid; Wlf[i] = dec1(sWl, i, fl); }
    else if (b == 32) { if (tid < 128) blf[tid] = dec1(sbl, tid, fl); }
    else if (b < 65) { int i = (b - 33) * 256 + tid; Wrf[i] = dec1(sWr, i, fl); }
    else if (b < 82) {
        int i = (b - 65) * 256 + tid;
        if (i < 4096) { int n = i >> 6, k = i & 63; WfT[n * DD + k] = dec1(hW, k * DD + n, fl); }
        else if (i < 4160) hbw[i - 4096] = dec1(hb, i - 4096, fl);
        else if (i < 4224) hbw[64 + (i - 4160)] = dec1(hW, 64 * DD + (i - 4160), fl);
    } else if (b < 131) {
        int i = (b - 82) * 256 + tid;
        if (i < 193 * DD) gWf[i] = dec1(gW, i, fl);
        else if (i < 194 * DD) gWf[i] = dec1(gb, i - 193 * DD, fl);
    } else if (b == 131) {
        if (tid < DD) linf[tid] = dec1(lW, tid, fl);
        else if (tid == DD) linf[DD] = dec1(lb, 0, fl);
    } else if (b < 388) {
        int i = (b - 132) * 256 + tid;
        int node = i >> 6, f = i & 63;
        h0[i] = dec1(emb, x[node] * DD + f, fl);
    } else if (b == 388) {
        // ---- CSR build, single block, register-batched ----
        for (int i = tid; i < NN; i += 256) sdeg[i] = 0;
        __syncthreads();
        // degree count: 8 independent loads per round
        for (int base = 0; base < EE; base += 2048) {
            int d8[8];
#pragma unroll
            for (int u = 0; u < 8; ++u) d8[u] = ei[EE + base + u * 256 + tid];
#pragma unroll
            for (int u = 0; u < 8; ++u) atomicAdd(&sdeg[d8[u]], 1);
        }
        __syncthreads();
        int base4 = tid * 4;
        int v[4]; int s = 0;
#pragma unroll
        for (int u = 0; u < 4; ++u) { v[u] = sdeg[base4 + u]; s += v[u]; }
        stmp[tid] = s;
        __syncthreads();
        for (int off = 1; off < 256; off <<= 1) {
            int a = (tid >= off) ? stmp[tid - off] : 0;
            __syncthreads();
            stmp[tid] += a;
            __syncthreads();
        }
        int run = stmp[tid] - s;
#pragma unroll
        for (int u = 0; u < 4; ++u) {
            rowptr[base4 + u] = run;
            sdeg[base4 + u] = run;    // becomes cursor
            run += v[u];
        }
        if (tid == 255) rowptr[NN] = run;
        __syncthreads();
        // scatter: 16 independent loads (8 dst + 8 src) per round
        for (int base = 0; base < EE; base += 2048) {
            int d8[8], s8[8];
#pragma unroll
            for (int u = 0; u < 8; ++u) {
                d8[u] = ei[EE + base + u * 256 + tid];
                s8[u] = ei[base + u * 256 + tid];
            }
#pragma unroll
            for (int u = 0; u < 8; ++u) {
                int c = atomicAdd(&sdeg[d8[u]], 1);
                csrc[c] = s8[u];
            }
        }
    }
}

// =============== shared SAGE body (one wave per node) ===============
static __device__ __forceinline__ void sage_body(
        char* smem, int node, int lane, int wave,
        const int* __restrict__ rowptr, const int* __restrict__ csrc,
        const float* __restrict__ hin,
        const float* __restrict__ Wl, const float* __restrict__ bl,
        const float* __restrict__ Wr,
        float* __restrict__ hout, unsigned short* __restrict__ hbf) {
    float* sa = (float*)smem + wave * 2 * DD;
    float* sh = sa + DD;
    int r0 = rowptr[node], r1 = rowptr[node + 1];
    float s = 0.f;
    for (int r = r0; r < r1; ++r) s += hin[csrc[r] * DD + lane];
    sa[lane] = s / (float)max(r1 - r0, 1);
    sh[lane] = hin[node * DD + lane];
    float o = bl[lane];
    for (int k = 0; k < DD; ++k)
        o += sa[k] * Wl[k * DD + lane] + sh[k] * Wr[k * DD + lane];
    float m = o;
    for (int off = 32; off; off >>= 1) m += __shfl_xor(m, off);
    m *= (1.f / DD);
    float d0 = o - m;
    float v = d0 * d0;
    for (int off = 32; off; off >>= 1) v += __shfl_xor(v, off);
    v *= (1.f / DD);
    float r = d0 * rsqrtf(v + EPSF);
    hout[node * DD + lane] = r;
    if (hbf) hbf[node * DD + lane] = f2bf_u(r);
}

// =============== K2: SAGE round 0 + edge-bitmap atomics ===============
__global__ __launch_bounds__(256) void k_sage0(
        const int* __restrict__ ei,
        const int* __restrict__ rowptr, const int* __restrict__ csrc,
        const float* __restrict__ h0,
        const float* __restrict__ Wlf, const float* __restrict__ blf,
        const float* __restrict__ Wrf,
        float* __restrict__ h1,
        unsigned int* __restrict__ eim, unsigned int* __restrict__ eimT) {
    __shared__ __align__(16) char smem[4 * 2 * DD * 4];
    const int b = blockIdx.x, tid = threadIdx.x;
    const int lane = tid & 63, wave = tid >> 6;
    if (tid < 64) {
        int e = b * 64 + tid;
        int s = ei[e], d = ei[EE + e];
        unsigned int idx = (unsigned int)(s * NN + d);
        atomicOr(&eim[idx >> 5], 1u << (idx & 31));
        unsigned int idxT = (unsigned int)(d * NN + s);
        atomicOr(&eimT[idxT >> 5], 1u << (idxT & 31));
    }
    sage_body(smem, b * 4 + wave, lane, wave, rowptr, csrc, h0, Wlf, blf, Wrf,
              h1, (unsigned short*)nullptr);
}

// =============== K3: SAGE round 1 (writes h2 + bf16 copy) ===============
__global__ __launch_bounds__(256) void k_sage1(
        const int* __restrict__ rowptr, const int* __restrict__ csrc,
        const float* __restrict__ h1,
        const float* __restrict__ Wlf, const float* __restrict__ blf,
        const float* __restrict__ Wrf,
        float* __restrict__ h2, unsigned short* __restrict__ hbf) {
    __shared__ __align__(16) char smem[4 * 2 * DD * 4];
    const int b = blockIdx.x, tid = threadIdx.x;
    const int lane = tid & 63, wave = tid >> 6;
    sage_body(smem, b * 4 + wave, lane, wave, rowptr, csrc, h1,
              Wlf + DD * DD, blf + DD, Wrf + DD * DD, h2, hbf);
}

// =============== K4: B-stage (MFMA) + fused pp/qq projection ===============
// NOTE: plain __launch_bounds__(256) — a (256,4) min-waves spec capped VGPR at 64
// and spilled ~100 live values to scratch (R8: WRITE 52 MB, FETCH 373 MB, 2.4x slower).
__global__ __launch_bounds__(256) void k_bstage(
        const float* __restrict__ h2, const unsigned short* __restrict__ hbf,
        const float* __restrict__ WfT, const float* __restrict__ hbw,
        const unsigned int* __restrict__ eim, const unsigned int* __restrict__ eimT,
        const float* __restrict__ gWf,
        float* __restrict__ ppb, float* __restrict__ qqb) {
    __shared__ __align__(16) unsigned short sW[DD * SWP];  // 9216 B
    __shared__ __align__(16) float red[4 * 128];           // 2048 B
    const int b = blockIdx.x, tid = threadIdx.x;
    const int lane = tid & 63, wave = tid >> 6;
    const int l15 = lane & 15, quad = lane >> 4;

    {
        int m = tid >> 2;
        int k0 = (tid & 3) * 16;
        const float* hi = h2 + b * DD;
        const float* wr = WfT + m * DD;
        unsigned short tmp[16];
#pragma unroll
        for (int u = 0; u < 16; ++u) tmp[u] = f2bf_u(hi[k0 + u] * wr[k0 + u]);
        *(short8*)(sW + m * SWP + k0) = *(short8*)tmp;
        *(short8*)(sW + m * SWP + k0 + 8) = *(short8*)(tmp + 8);
    }
    __syncthreads();

    short8 Af[4][2];
#pragma unroll
    for (int mt = 0; mt < 4; ++mt)
#pragma unroll
        for (int kt = 0; kt < 2; ++kt)
            Af[mt][kt] = *(const short8*)(sW + (mt * 16 + l15) * SWP + kt * 32 + quad * 8);

    float hb0[4][4], hww[4][4];
#pragma unroll
    for (int mt = 0; mt < 4; ++mt) {
        f32x4 a = *(const f32x4*)(hbw + mt * 16 + quad * 4);
        f32x4 wv = *(const f32x4*)(hbw + 64 + mt * 16 + quad * 4);
#pragma unroll
        for (int r = 0; r < 4; ++r) { hb0[mt][r] = a[r]; hww[mt][r] = wv[r]; }
    }

    float accf[4][4], accb[4][4];
#pragma unroll
    for (int mt = 0; mt < 4; ++mt)
#pragma unroll
        for (int r = 0; r < 4; ++r) { accf[mt][r] = 0.f; accb[mt][r] = 0.f; }

    int g = wave;
    short8 B0 = *(const short8*)(hbf + (g * 16 + l15) * DD + quad * 8);
    short8 B1 = *(const short8*)(hbf + (g * 16 + l15) * DD + 32 + quad * 8);

    for (int it = 0; it < 16; ++it, g += 4) {
        short8 cB0 = B0, cB1 = B1;
        if (it < 15) {
            int gn = g + 4;
            B0 = *(const short8*)(hbf + (gn * 16 + l15) * DD + quad * 8);
            B1 = *(const short8*)(hbf + (gn * 16 + l15) * DD + 32 + quad * 8);
        }
        unsigned int base = (unsigned int)(b * NN + g * 16);
        unsigned int sf = (eim[base >> 5] >> (base & 31)) & 0xFFFFu;
        unsigned int sb = (eimT[base >> 5] >> (base & 31)) & 0xFFFFu;

        f32x4 C[4];
#pragma unroll
        for (int mt = 0; mt < 4; ++mt)
            C[mt] = (f32x4){hb0[mt][0], hb0[mt][1], hb0[mt][2], hb0[mt][3]};
#pragma unroll
        for (int mt = 0; mt < 4; ++mt)
            C[mt] = __builtin_amdgcn_mfma_f32_16x16x32_bf16(Af[mt][0], cB0, C[mt], 0, 0, 0);
#pragma unroll
        for (int mt = 0; mt < 4; ++mt)
            C[mt] = __builtin_amdgcn_mfma_f32_16x16x32_bf16(Af[mt][1], cB1, C[mt], 0, 0, 0);

        float ef = (float)((sf >> l15) & 1u);
        float s1 = 0.f, s2 = 0.f;
#pragma unroll
        for (int mt = 0; mt < 4; ++mt)
#pragma unroll
            for (int r = 0; r < 4; ++r) {
                float v = C[mt][r] + ef * hww[mt][r];
                C[mt][r] = v;
                s1 += v;
                s2 += v * v;
            }
        s1 += __shfl_xor(s1, 16); s1 += __shfl_xor(s1, 32);
        s2 += __shfl_xor(s2, 16); s2 += __shfl_xor(s2, 32);
        float mean = s1 * (1.f / DD);
        float var = fmaxf(s2 * (1.f / DD) - mean * mean, 0.f);
        float rs = rsqrtf(var + EPSF);
        float mrs = mean * rs;

        if (sf == sb) {
#pragma unroll
            for (int mt = 0; mt < 4; ++mt)
#pragma unroll
                for (int r = 0; r < 4; ++r) {
                    float u = fmaxf(C[mt][r] * rs - mrs, 0.f);
                    accf[mt][r] += u;
                    accb[mt][r] += u;
                }
        } else {
#pragma unroll
            for (int mt = 0; mt < 4; ++mt)
#pragma unroll
                for (int r = 0; r < 4; ++r)
                    accf[mt][r] += fmaxf(C[mt][r] * rs - mrs, 0.f);
            float de = (float)((sb >> l15) & 1u) - ef;
            float t1 = 0.f, t2 = 0.f;
#pragma unroll
            for (int mt = 0; mt < 4; ++mt)
#pragma unroll
                for (int r = 0; r < 4; ++r) {
                    float v = C[mt][r] + de * hww[mt][r];
                    C[mt][r] = v;
                    t1 += v;
                    t2 += v * v;
                }
            t1 += __shfl_xor(t1, 16); t1 += __shfl_xor(t1, 32);
            t2 += __shfl_xor(t2, 16); t2 += __shfl_xor(t2, 32);
            float mean2 = t1 * (1.f / DD);
            float var2 = fmaxf(t2 * (1.f / DD) - mean2 * mean2, 0.f);
            float rs2 = rsqrtf(var2 + EPSF);
            float mrs2 = mean2 * rs2;
#pragma unroll
            for (int mt = 0; mt < 4; ++mt)
#pragma unroll
                for (int r = 0; r < 4; ++r)
                    accb[mt][r] += fmaxf(C[mt][r] * rs2 - mrs2, 0.f);
        }
    }

#pragma unroll
    for (int step = 1; step < 16; step <<= 1)
#pragma unroll
        for (int mt = 0; mt < 4; ++mt)
#pragma unroll
            for (int r = 0; r < 4; ++r) {
                accf[mt][r] += __shfl_xor(accf[mt][r], step);
                accb[mt][r] += __shfl_xor(accb[mt][r], step);
            }
    if (l15 == 0) {
#pragma unroll
        for (int mt = 0; mt < 4; ++mt)
#pragma unroll
            for (int r = 0; r < 4; ++r) {
                int m = mt * 16 + quad * 4 + r;
                red[wave * 128 + m] = accf[mt][r];
                red[wave * 128 + DD + m] = accb[mt][r];
            }
    }
    __syncthreads();
    if (tid < 128) {
        float sum = red[tid] + red[128 + tid] + red[256 + tid] + red[384 + tid];
        red[tid] = sum;
    }
    __syncthreads();
    if (wave < 2) {
        const float* sv = red + wave * DD;
        int row0 = wave ? 129 : 65;
        float o = 0.f;
        for (int k = 0; k < DD; ++k) o += sv[k] * gWf[(row0 + k) * DD + lane];
        (wave ? qqb : ppb)[b * DD + lane] = o;
    }
}

// =============== K5: final selected pairs (MFMA) ===============
__global__ __launch_bounds__(256) void k_final(
        const void* __restrict__ emb,
        const int* __restrict__ pos, const unsigned short* __restrict__ hbf,
        const float* __restrict__ gWf, const unsigned int* __restrict__ eim,
        const float* __restrict__ ppb, const float* __restrict__ qqb,
        const float* __restrict__ linf, void* __restrict__ outv) {
    __shared__ __align__(16) unsigned short sgW[DD * SWP];
    const int b = blockIdx.x, tid = threadIdx.x;
    const int lane = tid & 63, wave = tid >> 6;
    const int l15 = lane & 15, quad = lane >> 4;
    const int fl = probe_fl(emb);

    {
        int m = tid >> 2;
        int k0 = (tid & 3) * 16;
        unsigned short tmp[16];
#pragma unroll
        for (int u = 0; u < 16; ++u) tmp[u] = f2bf_u(gWf[(k0 + u) * DD + m]);
        *(short8*)(sgW + m * SWP + k0) = *(short8*)tmp;
        *(short8*)(sgW + m * SWP + k0 + 8) = *(short8*)(tmp + 8);
    }

    int pp_ = b * 64 + wave * 16 + l15;
    int a = pos[2 * pp_], bb = pos[2 * pp_ + 1];
    short8 ha0 = *(const short8*)(hbf + a * DD + quad * 8);
    short8 hb0v = *(const short8*)(hbf + bb * DD + quad * 8);
    short8 ha1 = *(const short8*)(hbf + a * DD + 32 + quad * 8);
    short8 hb1v = *(const short8*)(hbf + bb * DD + 32 + quad * 8);
    short8 B0, B1;
#pragma unroll
    for (int j = 0; j < 8; ++j) {
        B0[j] = (short)f2bf_u(bfu2f((unsigned short)ha0[j]) * bfu2f((unsigned short)hb0v[j]));
        B1[j] = (short)f2bf_u(bfu2f((unsigned short)ha1[j]) * bfu2f((unsigned short)hb1v[j]));
    }
    __syncthreads();

    f32x4 C[4];
#pragma unroll
    for (int mt = 0; mt < 4; ++mt) C[mt] = (f32x4){0.f, 0.f, 0.f, 0.f};
#pragma unroll
    for (int mt = 0; mt < 4; ++mt) {
        short8 A0 = *(const short8*)(sgW + (mt * 16 + l15) * SWP + quad * 8);
        C[mt] = __builtin_amdgcn_mfma_f32_16x16x32_bf16(A0, B0, C[mt], 0, 0, 0);
    }
#pragma unroll
    for (int mt = 0; mt < 4; ++mt) {
        short8 A1 = *(const short8*)(sgW + (mt * 16 + l15) * SWP + 32 + quad * 8);
        C[mt] = __builtin_amdgcn_mfma_f32_16x16x32_bf16(A1, B1, C[mt], 0, 0, 0);
    }

    unsigned int iab = (unsigned int)(a * NN + bb), iba = (unsigned int)(bb * NN + a);
    float eab = (float)((eim[iab >> 5] >> (iab & 31)) & 1u);
    float eba = (float)((eim[iba >> 5] >> (iba & 31)) & 1u);

    float u1[4][4], u2[4][4];
    float s1 = 0.f, s12 = 0.f, s2 = 0.f, s22 = 0.f;
#pragma unroll
    for (int mt = 0; mt < 4; ++mt) {
        int m0 = mt * 16 + quad * 4;
        f32x4 w64v = *(const f32x4*)(gWf + 64 * DD + m0);
        f32x4 gbv  = *(const f32x4*)(gWf + 193 * DD + m0);
        f32x4 ppa  = *(const f32x4*)(ppb + a * DD + m0);
        f32x4 qqb_ = *(const f32x4*)(qqb + bb * DD + m0);
        f32x4 ppb_ = *(const f32x4*)(ppb + bb * DD + m0);
        f32x4 qqa  = *(const f32x4*)(qqb + a * DD + m0);
#pragma unroll
        for (int r = 0; r < 4; ++r) {
            float v1 = C[mt][r] + eab * w64v[r] + ppa[r] + qqb_[r] + gbv[r];
            float v2 = C[mt][r] + eba * w64v[r] + ppb_[r] + qqa[r] + gbv[r];
            u1[mt][r] = v1; u2[mt][r] = v2;
            s1 += v1; s12 += v1 * v1;
            s2 += v2; s22 += v2 * v2;
        }
    }
    s1 += __shfl_xor(s1, 16);  s1 += __shfl_xor(s1, 32);
    s12 += __shfl_xor(s12, 16); s12 += __shfl_xor(s12, 32);
    s2 += __shfl_xor(s2, 16);  s2 += __shfl_xor(s2, 32);
    s22 += __shfl_xor(s22, 16); s22 += __shfl_xor(s22, 32);
    float mean1 = s1 * (1.f / DD);
    float rs1 = rsqrtf(fmaxf(s12 * (1.f / DD) - mean1 * mean1, 0.f) + EPSF);
    float mrs1 = mean1 * rs1;
    float mean2 = s2 * (1.f / DD);
    float rs2 = rsqrtf(fmaxf(s22 * (1.f / DD) - mean2 * mean2, 0.f) + EPSF);
    float mrs2 = mean2 * rs2;

    float r = 0.f;
#pragma unroll
    for (int mt = 0; mt < 4; ++mt) {
        f32x4 lw = *(const f32x4*)(linf + mt * 16 + quad * 4);
#pragma unroll
        for (int rr = 0; rr < 4; ++rr) {
            float g1 = fmaxf(u1[mt][rr] * rs1 - mrs1, 0.f);
            float g2 = fmaxf(u2[mt][rr] * rs2 - mrs2, 0.f);
            r += g1 * g2 * lw[rr];
        }
    }
    r += __shfl_xor(r, 16); r += __shfl_xor(r, 32);
    if (quad == 0) {
        float res = r + linf[DD];
        if (fl) ((float*)outv)[pp_] = res;
        else    ((bf16*)outv)[pp_] = __float2bfloat16(res);
    }
}

extern "C" void kernel_launch(void* const* d_in, const int* in_sizes, int n_in,
                              void* d_out, int out_size, void* d_ws, size_t ws_size,
                              hipStream_t stream) {
    const int* x   = (const int*)d_in[0];
    const int* ei  = (const int*)d_in[1];
    const int* pos = (const int*)d_in[2];
    const void* emb = d_in[3];

    char* w = (char*)d_ws;
    auto alloc = [&](size_t bytes) {
        void* q = (void*)w;
        w += (bytes + 255) & ~(size_t)255;
        return q;
    };
    unsigned int* eim  = (unsigned int*)alloc(NN * NN / 8);
    unsigned int* eimT = (unsigned int*)alloc(NN * NN / 8);
    float* h0   = (float*)alloc(NN * DD * 4);
    float* h1   = (float*)alloc(NN * DD * 4);
    float* h2   = (float*)alloc(NN * DD * 4);
    unsigned short* hbf = (unsigned short*)alloc(NN * DD * 2);
    float* Wlf  = (float*)alloc(2 * DD * DD * 4);
    float* blf  = (float*)alloc(2 * DD * 4);
    float* Wrf  = (float*)alloc(2 * DD * DD * 4);
    float* WfT  = (float*)alloc(DD * DD * 4);
    float* hbw  = (float*)alloc(128 * 4);
    float* gWf  = (float*)alloc(194 * DD * 4);
    float* linf = (float*)alloc(65 * 4);
    float* ppb  = (float*)alloc(NN * DD * 4);
    float* qqb  = (float*)alloc(NN * DD * 4);
    int* rowptr = (int*)alloc((NN + 1) * 4);
    int* csrc   = (int*)alloc(EE * 4);

    k_prep<<<389, 256, 0, stream>>>(emb, d_in[4], d_in[5], d_in[6], d_in[7], d_in[8],
                                    d_in[9], d_in[10], d_in[11], d_in[12],
                                    x, ei, Wlf, blf, Wrf, WfT, hbw, gWf, linf,
                                    h0, eim, eimT, rowptr, csrc);
    k_sage0<<<256, 256, 0, stream>>>(ei, rowptr, csrc, h0, Wlf, blf, Wrf, h1, eim, eimT);
    k_sage1<<<256, 256, 0, stream>>>(rowptr, csrc, h1, Wlf, blf, Wrf, h2, hbf);
    k_bstage<<<NN, 256, 0, stream>>>(h2, hbf, WfT, hbw, eim, eimT, gWf, ppb, qqb);
    k_final<<<PP / 64, 256, 0, stream>>>(emb, pos, hbf, gWf, eim, ppb, qqb, linf, d_out);
}